// Round 1
// baseline (2617.298 us; speedup 1.0000x reference)
//
#include <hip/hip_runtime.h>

#define B_ 8
#define T_ 1024
#define D_ 512
#define H_ 8
#define DK_ 64

// ---------------------------------------------------------------------------
// Kernel 1/3: fp32 SGEMM  C[M,512] = X[M,512] @ W[512,512] (+ bias)
// scatter=1: write to [B,H,T,DK] layout (proj); scatter=0: plain row-major.
// Tiles: 64x64x16, 256 threads, 4x4 microtile per thread.
// ---------------------------------------------------------------------------
__global__ __launch_bounds__(256) void gemm512(const float* __restrict__ X,
                                               const float* __restrict__ W,
                                               const float* __restrict__ bias,
                                               float* __restrict__ out,
                                               int scatter) {
  __shared__ float As[16][68];  // [k][m], padded row stride 68 (16B aligned)
  __shared__ float Bs[16][64];  // [k][n]

  const int tid = threadIdx.x;
  const int tx = tid & 15, ty = tid >> 4;
  const int m0 = blockIdx.y * 64, n0 = blockIdx.x * 64;

  // loader indices
  const int arow = tid >> 2;         // 0..63  (m within tile)
  const int akq  = (tid & 3) * 4;    // k offset 0,4,8,12
  const int bkk  = tid >> 4;         // 0..15  (k within tile)
  const int bn   = (tid & 15) * 4;   // n offset

  float c[4][4];
#pragma unroll
  for (int i = 0; i < 4; ++i)
#pragma unroll
    for (int j = 0; j < 4; ++j) c[i][j] = 0.f;

  for (int k0 = 0; k0 < 512; k0 += 16) {
    float4 av = *(const float4*)(X + (size_t)(m0 + arow) * 512 + k0 + akq);
    float4 bv = *(const float4*)(W + (size_t)(k0 + bkk) * 512 + n0 + bn);
    __syncthreads();  // protect previous iteration's reads
    As[akq + 0][arow] = av.x;
    As[akq + 1][arow] = av.y;
    As[akq + 2][arow] = av.z;
    As[akq + 3][arow] = av.w;
    *(float4*)&Bs[bkk][bn] = bv;
    __syncthreads();
#pragma unroll
    for (int kk = 0; kk < 16; ++kk) {
      float4 a = *(const float4*)&As[kk][ty * 4];
      float4 b = *(const float4*)&Bs[kk][tx * 4];
      c[0][0] = fmaf(a.x, b.x, c[0][0]); c[0][1] = fmaf(a.x, b.y, c[0][1]);
      c[0][2] = fmaf(a.x, b.z, c[0][2]); c[0][3] = fmaf(a.x, b.w, c[0][3]);
      c[1][0] = fmaf(a.y, b.x, c[1][0]); c[1][1] = fmaf(a.y, b.y, c[1][1]);
      c[1][2] = fmaf(a.y, b.z, c[1][2]); c[1][3] = fmaf(a.y, b.w, c[1][3]);
      c[2][0] = fmaf(a.z, b.x, c[2][0]); c[2][1] = fmaf(a.z, b.y, c[2][1]);
      c[2][2] = fmaf(a.z, b.z, c[2][2]); c[2][3] = fmaf(a.z, b.w, c[2][3]);
      c[3][0] = fmaf(a.w, b.x, c[3][0]); c[3][1] = fmaf(a.w, b.y, c[3][1]);
      c[3][2] = fmaf(a.w, b.z, c[3][2]); c[3][3] = fmaf(a.w, b.w, c[3][3]);
    }
  }

  float4 bias4 = make_float4(0.f, 0.f, 0.f, 0.f);
  if (bias) bias4 = *(const float4*)(bias + n0 + tx * 4);

#pragma unroll
  for (int ii = 0; ii < 4; ++ii) {
    const int mrow = m0 + ty * 4 + ii;
    float4 r;
    r.x = c[ii][0] + bias4.x;
    r.y = c[ii][1] + bias4.y;
    r.z = c[ii][2] + bias4.z;
    r.w = c[ii][3] + bias4.w;
    if (scatter) {
      // row m -> (b = m/T, t = m%T); col n -> (h = n/DK, dk = n%DK)
      const int bb = mrow >> 10, tt = mrow & 1023;
      const int hh = n0 >> 6;  // tile width == DK
      *(float4*)(out + ((size_t)((bb * H_ + hh) * T_ + tt)) * DK_ + tx * 4) = r;
    } else {
      *(float4*)(out + (size_t)mrow * 512 + n0 + tx * 4) = r;
    }
  }
}

// ---------------------------------------------------------------------------
// Kernel 2: fused attention with Transformer-XL rel-shift.
// Block = 256 threads: 32 i-rows x 8 j-split. Streams j in tiles of 64 with
// online softmax; per-thread partials merged via LDS atomics.
//
// shifted_pos[i,j] = raw[i,   T-1+j-i]   if j <= i
//                  = 0                   if j == i+1
//                  = raw[i+1, j-i-2]     if j >  i+1   (rel_shift artifact!)
// where raw[r,c] = (q_r + v_bias) . p_c
// ---------------------------------------------------------------------------
__global__ __launch_bounds__(256) void attn_kernel(
    const float* __restrict__ qb, const float* __restrict__ kb,
    const float* __restrict__ vb, const float* __restrict__ pb,
    const float* __restrict__ ubias, const float* __restrict__ vbias,
    float* __restrict__ ctx) {
  constexpr float SCALE = 0.044194173824159216f;  // 1/sqrt(512) (d_model!)

  const int i0 = blockIdx.x * 32;
  const int h = blockIdx.y;
  const int b = blockIdx.z;
  const int tid = threadIdx.x;
  const int i_loc = tid >> 3;  // 0..31
  const int jg = tid & 7;      // 0..7
  const int i = i0 + i_loc;

  __shared__ float smem[13124];
  float* Qu = smem;             // [32][68]  q + u_bias
  float* Qv = Qu + 32 * 68;     // [33][68]  q + v_bias (extra boundary row)
  float* Ks = Qv + 33 * 68;     // [64][68]
  float* Vs = Ks + 64 * 68;     // [64][68]

  const size_t bh = (size_t)(b * H_ + h) * T_ * DK_;
  const float* Q = qb + bh;
  const float* Kg = kb + bh;
  const float* Vg = vb + bh;
  const float* Pg = pb + bh;

  // stage Qu (32 rows), Qv (33 rows) with bias add
  for (int f4 = tid; f4 < 32 * 16; f4 += 256) {
    const int r = f4 >> 4, cc = (f4 & 15) * 4;
    float4 q4 = *(const float4*)(Q + (size_t)(i0 + r) * DK_ + cc);
    float4 u4 = *(const float4*)(ubias + h * DK_ + cc);
    float4 o;
    o.x = q4.x + u4.x; o.y = q4.y + u4.y; o.z = q4.z + u4.z; o.w = q4.w + u4.w;
    *(float4*)&Qu[r * 68 + cc] = o;
  }
  for (int f4 = tid; f4 < 33 * 16; f4 += 256) {
    const int r = f4 >> 4, cc = (f4 & 15) * 4;
    const int gr = i0 + r;
    if (gr < T_) {
      float4 q4 = *(const float4*)(Q + (size_t)gr * DK_ + cc);
      float4 v4 = *(const float4*)(vbias + h * DK_ + cc);
      float4 o;
      o.x = q4.x + v4.x; o.y = q4.y + v4.y; o.z = q4.z + v4.z; o.w = q4.w + v4.w;
      *(float4*)&Qv[r * 68 + cc] = o;
    }
  }

  float m = -INFINITY, l = 0.f;
  float o_[64];
#pragma unroll
  for (int d = 0; d < 64; ++d) o_[d] = 0.f;

  const float4* qu4 = (const float4*)&Qu[i_loc * 68];

  for (int jt = 0; jt < 16; ++jt) {
    const int j0 = jt * 64;
    __syncthreads();
#pragma unroll
    for (int cload = 0; cload < 4; ++cload) {
      const int f4 = cload * 256 + tid;
      const int r = f4 >> 4, cc = (f4 & 15) * 4;
      *(float4*)&Ks[r * 68 + cc] = *(const float4*)(Kg + (size_t)(j0 + r) * DK_ + cc);
      *(float4*)&Vs[r * 68 + cc] = *(const float4*)(Vg + (size_t)(j0 + r) * DK_ + cc);
    }
    __syncthreads();

    float s[8];
#pragma unroll
    for (int q = 0; q < 8; ++q) {
      const int jl = jg + 8 * q;  // strided: wave lanes hit distinct banks
      const int j = j0 + jl;
      const float4* k4 = (const float4*)&Ks[jl * 68];
      float acc = 0.f;
#pragma unroll
      for (int dc = 0; dc < 16; ++dc) {
        float4 a = qu4[dc], kk = k4[dc];
        acc = fmaf(a.x, kk.x, acc); acc = fmaf(a.y, kk.y, acc);
        acc = fmaf(a.z, kk.z, acc); acc = fmaf(a.w, kk.w, acc);
      }
      const int rel = j - i;
      if (rel != 1) {
        int qr, pidx;
        if (rel <= 0) { qr = i_loc; pidx = T_ - 1 + rel; }
        else          { qr = i_loc + 1; pidx = rel - 2; }
        const float4* qv4 = (const float4*)&Qv[qr * 68];
        const float4* p4 = (const float4*)(Pg + (size_t)pidx * DK_);
        float accp = 0.f;
#pragma unroll
        for (int dc = 0; dc < 16; ++dc) {
          float4 a = qv4[dc], pp = p4[dc];
          accp = fmaf(a.x, pp.x, accp); accp = fmaf(a.y, pp.y, accp);
          accp = fmaf(a.z, pp.z, accp); accp = fmaf(a.w, pp.w, accp);
        }
        acc += accp;
      }
      s[q] = acc * SCALE;
    }

    // online softmax update
    float tm = s[0];
#pragma unroll
    for (int q = 1; q < 8; ++q) tm = fmaxf(tm, s[q]);
    if (tm > m) {
      const float r = __expf(m - tm);  // m=-inf first time -> r=0
      l *= r;
#pragma unroll
      for (int d = 0; d < 64; ++d) o_[d] *= r;
      m = tm;
    }
#pragma unroll
    for (int q = 0; q < 8; ++q) {
      const int jl = jg + 8 * q;
      const float w = __expf(s[q] - m);
      l += w;
      const float4* v4 = (const float4*)&Vs[jl * 68];
#pragma unroll
      for (int dc = 0; dc < 16; ++dc) {
        float4 vv = v4[dc];
        o_[4 * dc + 0] = fmaf(w, vv.x, o_[4 * dc + 0]);
        o_[4 * dc + 1] = fmaf(w, vv.y, o_[4 * dc + 1]);
        o_[4 * dc + 2] = fmaf(w, vv.z, o_[4 * dc + 2]);
        o_[4 * dc + 3] = fmaf(w, vv.w, o_[4 * dc + 3]);
      }
    }
  }

  // ---- merge the 8 j-split partials per row (reuse LDS) ----
  __syncthreads();
  float* rowO = Ks;        // 32*64
  float* redm = Vs;        // 32*8
  float* rowL = Vs + 256;  // 32
  for (int idx = tid; idx < 32 * 64; idx += 256) rowO[idx] = 0.f;
  if (tid < 32) rowL[tid] = 0.f;
  redm[i_loc * 8 + jg] = m;
  __syncthreads();
  float M = redm[i_loc * 8];
#pragma unroll
  for (int q = 1; q < 8; ++q) M = fmaxf(M, redm[i_loc * 8 + q]);
  const float f = __expf(m - M);
  atomicAdd(&rowL[i_loc], l * f);
#pragma unroll
  for (int d = 0; d < 64; ++d) atomicAdd(&rowO[i_loc * 64 + d], o_[d] * f);
  __syncthreads();

  for (int f4 = tid; f4 < 512; f4 += 256) {
    const int r = f4 >> 4, cc = (f4 & 15) * 4;
    const float inv = 1.0f / rowL[r];
    float4 o4;
    o4.x = rowO[r * 64 + cc + 0] * inv;
    o4.y = rowO[r * 64 + cc + 1] * inv;
    o4.z = rowO[r * 64 + cc + 2] * inv;
    o4.w = rowO[r * 64 + cc + 3] * inv;
    *(float4*)(ctx + (size_t)(b * T_ + i0 + r) * D_ + h * DK_ + cc) = o4;
  }
}

// ---------------------------------------------------------------------------
extern "C" void kernel_launch(void* const* d_in, const int* in_sizes, int n_in,
                              void* d_out, int out_size, void* d_ws,
                              size_t ws_size, hipStream_t stream) {
  const float* query = (const float*)d_in[0];
  const float* key   = (const float*)d_in[1];
  const float* value = (const float*)d_in[2];
  const float* pos   = (const float*)d_in[3];
  const float* Wq = (const float*)d_in[4];
  const float* bq = (const float*)d_in[5];
  const float* Wk = (const float*)d_in[6];
  const float* bk = (const float*)d_in[7];
  const float* Wv = (const float*)d_in[8];
  const float* bv = (const float*)d_in[9];
  const float* Wp = (const float*)d_in[10];
  const float* ub = (const float*)d_in[11];
  const float* vbias = (const float*)d_in[12];
  const float* Wo = (const float*)d_in[13];
  const float* bo = (const float*)d_in[14];
  float* out = (float*)d_out;

  const size_t NBHTD = (size_t)B_ * H_ * T_ * DK_;  // 4194304
  float* ws = (float*)d_ws;
  float* qb = ws;
  float* kb = qb + NBHTD;
  float* vb = kb + NBHTD;
  float* pb = vb + NBHTD;
  float* ctx = pb + NBHTD;  // [B*T, D]   total 80 MB fp32

  dim3 gdim(8, 128);  // N/64, M/64
  gemm512<<<gdim, 256, 0, stream>>>(query, Wq, bq, qb, 1);
  gemm512<<<gdim, 256, 0, stream>>>(key, Wk, bk, kb, 1);
  gemm512<<<gdim, 256, 0, stream>>>(value, Wv, bv, vb, 1);
  gemm512<<<gdim, 256, 0, stream>>>(pos, Wp, nullptr, pb, 1);

  attn_kernel<<<dim3(T_ / 32, H_, B_), 256, 0, stream>>>(qb, kb, vb, pb, ub,
                                                         vbias, ctx);

  gemm512<<<gdim, 256, 0, stream>>>(ctx, Wo, bo, out, 0);
}

// Round 2
// 411.268 us; speedup vs baseline: 6.3640x; 6.3640x over previous
//
#include <hip/hip_runtime.h>

#define B_ 8
#define T_ 1024
#define D_ 512
#define H_ 8
#define DK_ 64

typedef __bf16 bf16x8 __attribute__((ext_vector_type(8)));
typedef float f32x4 __attribute__((ext_vector_type(4)));

#define MFMA16(a, b, c) __builtin_amdgcn_mfma_f32_16x16x32_bf16(a, b, c, 0, 0, 0)

__device__ __forceinline__ bf16x8 pack8(float4 a, float4 b) {
  bf16x8 r;
  r[0] = (__bf16)a.x; r[1] = (__bf16)a.y; r[2] = (__bf16)a.z; r[3] = (__bf16)a.w;
  r[4] = (__bf16)b.x; r[5] = (__bf16)b.y; r[6] = (__bf16)b.z; r[7] = (__bf16)b.w;
  return r;
}
__device__ __forceinline__ float4 add4(float4 a, float4 b) {
  return make_float4(a.x + b.x, a.y + b.y, a.z + b.z, a.w + b.w);
}

// ---------------------------------------------------------------------------
// bf16-MFMA GEMM: C[M,512] = X[M,512] @ W[512,512] (+bias), M = 8192.
// Tile 128x64, 256 thr = 4 waves, wave -> 32 rows (2 row-blocks), K-step 32.
// LDS: As[m][k] row-stride 40 bf16 (80 B, 2-way banks), Bs stored [n][k].
// scatter=1 -> write [B,H,T,DK]; scatter=0 -> row-major.
// ---------------------------------------------------------------------------
__global__ __launch_bounds__(256) void gemm_mfma(const float* __restrict__ X,
                                                 const float* __restrict__ W,
                                                 const float* __restrict__ bias,
                                                 float* __restrict__ out,
                                                 int scatter) {
  __shared__ __bf16 As[128 * 40];
  __shared__ __bf16 Bs[64 * 40];
  const int tid = threadIdx.x;
  const int wave = tid >> 6, lane = tid & 63, l16 = lane & 15, quad = lane >> 4;
  const int m0 = blockIdx.y * 128, n0 = blockIdx.x * 64;

  f32x4 acc[2][4];
#pragma unroll
  for (int rb = 0; rb < 2; ++rb)
#pragma unroll
    for (int cb = 0; cb < 4; ++cb) acc[rb][cb] = 0.f;

  const int arow = tid >> 1, ako = (tid & 1) * 16;   // A: 128 rows x 32 k
  const int bn = tid & 63, bko = (tid >> 6) * 8;     // B: 64 n x 32 k

  for (int k0 = 0; k0 < 512; k0 += 32) {
    const float* xp = X + (size_t)(m0 + arow) * 512 + k0 + ako;
    const float4 a0 = *(const float4*)(xp);
    const float4 a1 = *(const float4*)(xp + 4);
    const float4 a2 = *(const float4*)(xp + 8);
    const float4 a3 = *(const float4*)(xp + 12);
    float wv[8];
#pragma unroll
    for (int q = 0; q < 8; ++q) wv[q] = W[(size_t)(k0 + bko + q) * 512 + n0 + bn];

    __syncthreads();  // previous iteration's fragment reads done
    *(bf16x8*)&As[arow * 40 + ako] = pack8(a0, a1);
    *(bf16x8*)&As[arow * 40 + ako + 8] = pack8(a2, a3);
    bf16x8 wb;
#pragma unroll
    for (int q = 0; q < 8; ++q) wb[q] = (__bf16)wv[q];
    *(bf16x8*)&Bs[bn * 40 + bko] = wb;
    __syncthreads();

    bf16x8 af0 = *(const bf16x8*)&As[(wave * 32 + l16) * 40 + quad * 8];
    bf16x8 af1 = *(const bf16x8*)&As[(wave * 32 + 16 + l16) * 40 + quad * 8];
#pragma unroll
    for (int cb = 0; cb < 4; ++cb) {
      bf16x8 bf = *(const bf16x8*)&Bs[(cb * 16 + l16) * 40 + quad * 8];
      acc[0][cb] = MFMA16(af0, bf, acc[0][cb]);
      acc[1][cb] = MFMA16(af1, bf, acc[1][cb]);
    }
  }

#pragma unroll
  for (int rb = 0; rb < 2; ++rb)
#pragma unroll
    for (int cb = 0; cb < 4; ++cb) {
      const int col = n0 + cb * 16 + l16;
      const float bv = bias ? bias[col] : 0.f;
#pragma unroll
      for (int r = 0; r < 4; ++r) {
        const int row = m0 + wave * 32 + rb * 16 + quad * 4 + r;
        const float v = acc[rb][cb][r] + bv;
        if (scatter) {
          const int bb = row >> 10, tt = row & 1023, hh = col >> 6, dk = col & 63;
          out[(((size_t)(bb * H_ + hh)) * T_ + tt) * DK_ + dk] = v;
        } else {
          out[(size_t)row * 512 + col] = v;
        }
      }
    }
}

// ---------------------------------------------------------------------------
// Fused MFMA attention with Transformer-XL rel-shift.
// Block: 4 waves, i-tile 64 rows; j streamed in 16 tiles of 64.
// Pos score via in-LDS band GEMM R[65x128] = Qv . Pband^T where
// band col o' <-> P row (cstart + o') mod T, cstart = T-65+j0-i0, and
// shifted[i,j] = (j-i==1) ? 0 : R[di + (j-i>=2)][dj - rr + 64].
// ---------------------------------------------------------------------------
__global__ __launch_bounds__(256) void attn_mfma(
    const float* __restrict__ qb, const float* __restrict__ kb,
    const float* __restrict__ vb, const float* __restrict__ pb,
    const float* __restrict__ ub, const float* __restrict__ vbias,
    float* __restrict__ ctx) {
  constexpr float SCALE = 0.044194173824159216f;  // 1/sqrt(512) (d_model)
  __shared__ __bf16 Kt[64 * 72];   // K[j][k]
  __shared__ __bf16 Vt[64 * 72];   // V^T[d][j]
  __shared__ __bf16 Pb[128 * 72];  // P band [o'][k]; aliased as Pa[64][72]
  __shared__ __bf16 Rm[80 * 136];  // R band scores [rr][o']

  const int tid = threadIdx.x;
  const int wave = tid >> 6, lane = tid & 63, l16 = lane & 15, quad = lane >> 4;
  const int i0 = blockIdx.x * 64, h = blockIdx.y, b = blockIdx.z;
  const size_t bh = ((size_t)(b * H_ + h)) * T_ * DK_;
  const float* Q = qb + bh;
  const float* Kg = kb + bh;
  const float* Vg = vb + bh;
  const float* Pg = pb + bh;

  // A-fragments held in registers for the whole kernel.
  bf16x8 quA[2], qvw[2], qv4[2];
  {
    const int rw = i0 + wave * 16 + l16;          // rows of this wave's strip
    const int r4 = min(i0 + 64 + l16, T_ - 1);    // band rows 64..79 (row 64 real)
#pragma unroll
    for (int s = 0; s < 2; ++s) {
      const int ko = s * 32 + quad * 8;
      const float4 q0 = *(const float4*)(Q + (size_t)rw * DK_ + ko);
      const float4 q1 = *(const float4*)(Q + (size_t)rw * DK_ + ko + 4);
      const float4 u0 = *(const float4*)(ub + h * DK_ + ko);
      const float4 u1 = *(const float4*)(ub + h * DK_ + ko + 4);
      const float4 v0 = *(const float4*)(vbias + h * DK_ + ko);
      const float4 v1 = *(const float4*)(vbias + h * DK_ + ko + 4);
      quA[s] = pack8(add4(q0, u0), add4(q1, u1));
      qvw[s] = pack8(add4(q0, v0), add4(q1, v1));
      const float4 x0 = *(const float4*)(Q + (size_t)r4 * DK_ + ko);
      const float4 x1 = *(const float4*)(Q + (size_t)r4 * DK_ + ko + 4);
      qv4[s] = pack8(add4(x0, v0), add4(x1, v1));
    }
  }

  f32x4 Oacc[4];
#pragma unroll
  for (int cb = 0; cb < 4; ++cb) Oacc[cb] = 0.f;
  float mrun[4], lrun[4];
#pragma unroll
  for (int r = 0; r < 4; ++r) { mrun[r] = -INFINITY; lrun[r] = 0.f; }

  for (int jt = 0; jt < 16; ++jt) {
    const int j0 = jt * 64;
    int cstart = T_ - 65 + j0 - i0;
    if (cstart < 0) cstart += T_;
    if (cstart >= T_) cstart -= T_;

    __syncthreads();  // previous iteration's LDS reads complete
    {  // stage K tile [j][k]
      const int r = tid >> 2, ko = (tid & 3) * 16;
      const float* src = Kg + (size_t)(j0 + r) * DK_ + ko;
      *(bf16x8*)&Kt[r * 72 + ko] =
          pack8(*(const float4*)src, *(const float4*)(src + 4));
      *(bf16x8*)&Kt[r * 72 + ko + 8] =
          pack8(*(const float4*)(src + 8), *(const float4*)(src + 12));
    }
    {  // stage V transposed [d][j]
      const int d = tid & 63, jb = (tid >> 6) * 16;
      bf16x8 w0, w1;
#pragma unroll
      for (int q = 0; q < 8; ++q)
        w0[q] = (__bf16)Vg[(size_t)(j0 + jb + q) * DK_ + d];
#pragma unroll
      for (int q = 0; q < 8; ++q)
        w1[q] = (__bf16)Vg[(size_t)(j0 + jb + 8 + q) * DK_ + d];
      *(bf16x8*)&Vt[d * 72 + jb] = w0;
      *(bf16x8*)&Vt[d * 72 + jb + 8] = w1;
    }
    {  // stage P band [o'][k]
      const int o = tid >> 1, ko = (tid & 1) * 32;
      int prow = cstart + o;
      if (prow >= T_) prow -= T_;
      const float* src = Pg + (size_t)prow * DK_ + ko;
#pragma unroll
      for (int q = 0; q < 4; ++q) {
        *(bf16x8*)&Pb[o * 72 + ko + q * 8] =
            pack8(*(const float4*)(src + q * 8), *(const float4*)(src + q * 8 + 4));
      }
    }
    __syncthreads();

    // ---- S = Qu K^T for this wave's 16-row strip ----
    f32x4 sA[4];
#pragma unroll
    for (int cb = 0; cb < 4; ++cb) sA[cb] = 0.f;
#pragma unroll
    for (int s = 0; s < 2; ++s)
#pragma unroll
      for (int cb = 0; cb < 4; ++cb) {
        bf16x8 bf = *(const bf16x8*)&Kt[(cb * 16 + l16) * 72 + s * 32 + quad * 8];
        sA[cb] = MFMA16(quA[s], bf, sA[cb]);
      }

    // ---- R band GEMM: rows wave*16..+15 x 128 cols ----
#pragma unroll
    for (int cb = 0; cb < 8; ++cb) {
      f32x4 rc = 0.f;
#pragma unroll
      for (int s = 0; s < 2; ++s) {
        bf16x8 bf = *(const bf16x8*)&Pb[(cb * 16 + l16) * 72 + s * 32 + quad * 8];
        rc = MFMA16(qvw[s], bf, rc);
      }
      const int row = wave * 16 + quad * 4, col = cb * 16 + l16;
#pragma unroll
      for (int rr = 0; rr < 4; ++rr) Rm[(row + rr) * 136 + col] = (__bf16)rc[rr];
    }
    // rows 64..79 (only 64 used): 2 col-blocks per wave
#pragma unroll
    for (int c2 = 0; c2 < 2; ++c2) {
      const int cb = wave * 2 + c2;
      f32x4 rc = 0.f;
#pragma unroll
      for (int s = 0; s < 2; ++s) {
        bf16x8 bf = *(const bf16x8*)&Pb[(cb * 16 + l16) * 72 + s * 32 + quad * 8];
        rc = MFMA16(qv4[s], bf, rc);
      }
      const int row = 64 + quad * 4, col = cb * 16 + l16;
#pragma unroll
      for (int rr = 0; rr < 4; ++rr) Rm[(row + rr) * 136 + col] = (__bf16)rc[rr];
    }
    __syncthreads();

    // ---- gather rel-shifted pos score, scale ----
#pragma unroll
    for (int cb = 0; cb < 4; ++cb)
#pragma unroll
      for (int r = 0; r < 4; ++r) {
        const int di = wave * 16 + quad * 4 + r;
        const int dj = cb * 16 + l16;
        const int ji = (j0 + dj) - (i0 + di);
        float pos = 0.f;
        if (ji != 1) {
          const int rr = di + (ji >= 2 ? 1 : 0);
          const int op = dj - rr + 64;
          pos = (float)Rm[rr * 136 + op];
        }
        sA[cb][r] = (sA[cb][r] + pos) * SCALE;
      }

    // ---- online softmax (rows span 16 lanes of this quad-group) ----
    __bf16* Pa = Pb;  // alias: Pb reads finished at the barrier above
#pragma unroll
    for (int r = 0; r < 4; ++r) {
      float tm = fmaxf(fmaxf(sA[0][r], sA[1][r]), fmaxf(sA[2][r], sA[3][r]));
      tm = fmaxf(tm, __shfl_xor(tm, 1));
      tm = fmaxf(tm, __shfl_xor(tm, 2));
      tm = fmaxf(tm, __shfl_xor(tm, 4));
      tm = fmaxf(tm, __shfl_xor(tm, 8));
      const float nm = fmaxf(mrun[r], tm);
      const float alpha = __expf(mrun[r] - nm);  // first tile: exp(-inf)=0
      mrun[r] = nm;
      lrun[r] *= alpha;
#pragma unroll
      for (int cb = 0; cb < 4; ++cb) {
        Oacc[cb][r] *= alpha;
        const float w_ = __expf(sA[cb][r] - nm);
        lrun[r] += w_;
        Pa[(wave * 16 + quad * 4 + r) * 72 + cb * 16 + l16] = (__bf16)w_;
      }
    }

    // ---- O += Pa @ V (Pa rows are wave-local; waitcnt suffices) ----
#pragma unroll
    for (int s = 0; s < 2; ++s) {
      bf16x8 ap = *(const bf16x8*)&Pa[(wave * 16 + l16) * 72 + s * 32 + quad * 8];
#pragma unroll
      for (int cb = 0; cb < 4; ++cb) {
        bf16x8 bv = *(const bf16x8*)&Vt[(cb * 16 + l16) * 72 + s * 32 + quad * 8];
        Oacc[cb] = MFMA16(ap, bv, Oacc[cb]);
      }
    }
  }

  // ---- epilogue: row-sum l across the 16 lanes, normalize, store ----
  float inv[4];
#pragma unroll
  for (int r = 0; r < 4; ++r) {
    float L = lrun[r];
    L += __shfl_xor(L, 1);
    L += __shfl_xor(L, 2);
    L += __shfl_xor(L, 4);
    L += __shfl_xor(L, 8);
    inv[r] = 1.f / L;
  }
#pragma unroll
  for (int cb = 0; cb < 4; ++cb)
#pragma unroll
    for (int r = 0; r < 4; ++r) {
      const int row = i0 + wave * 16 + quad * 4 + r;
      const int col = h * DK_ + cb * 16 + l16;
      ctx[((size_t)(b * T_ + row)) * D_ + col] = Oacc[cb][r] * inv[r];
    }
}

// ---------------------------------------------------------------------------
extern "C" void kernel_launch(void* const* d_in, const int* in_sizes, int n_in,
                              void* d_out, int out_size, void* d_ws,
                              size_t ws_size, hipStream_t stream) {
  const float* query = (const float*)d_in[0];
  const float* key   = (const float*)d_in[1];
  const float* value = (const float*)d_in[2];
  const float* pos   = (const float*)d_in[3];
  const float* Wq = (const float*)d_in[4];
  const float* bq = (const float*)d_in[5];
  const float* Wk = (const float*)d_in[6];
  const float* bk = (const float*)d_in[7];
  const float* Wv = (const float*)d_in[8];
  const float* bv = (const float*)d_in[9];
  const float* Wp = (const float*)d_in[10];
  const float* ub = (const float*)d_in[11];
  const float* vbias = (const float*)d_in[12];
  const float* Wo = (const float*)d_in[13];
  const float* bo = (const float*)d_in[14];
  float* out = (float*)d_out;

  const size_t NBHTD = (size_t)B_ * H_ * T_ * DK_;  // 4194304
  float* ws = (float*)d_ws;
  float* qb = ws;
  float* kb = qb + NBHTD;
  float* vb = kb + NBHTD;
  float* pb = vb + NBHTD;
  float* ctx = pb + NBHTD;  // [B*T, D]; total 80 MB fp32

  const dim3 gg(8, 64);  // N/64, M/128
  gemm_mfma<<<gg, 256, 0, stream>>>(query, Wq, bq, qb, 1);
  gemm_mfma<<<gg, 256, 0, stream>>>(key, Wk, bk, kb, 1);
  gemm_mfma<<<gg, 256, 0, stream>>>(value, Wv, bv, vb, 1);
  gemm_mfma<<<gg, 256, 0, stream>>>(pos, Wp, nullptr, pb, 1);

  attn_mfma<<<dim3(T_ / 64, H_, B_), 256, 0, stream>>>(qb, kb, vb, pb, ub,
                                                       vbias, ctx);

  gemm_mfma<<<gg, 256, 0, stream>>>(ctx, Wo, bo, out, 0);
}

// Round 3
// 350.751 us; speedup vs baseline: 7.4620x; 1.1725x over previous
//
#include <hip/hip_runtime.h>

#define B_ 8
#define T_ 1024
#define D_ 512
#define H_ 8
#define DK_ 64

typedef __bf16 bf16x8 __attribute__((ext_vector_type(8)));
typedef float f32x4 __attribute__((ext_vector_type(4)));

#define MFMA16(a, b, c) __builtin_amdgcn_mfma_f32_16x16x32_bf16(a, b, c, 0, 0, 0)

__device__ __forceinline__ bf16x8 pack8(float4 a, float4 b) {
  bf16x8 r;
  r[0] = (__bf16)a.x; r[1] = (__bf16)a.y; r[2] = (__bf16)a.z; r[3] = (__bf16)a.w;
  r[4] = (__bf16)b.x; r[5] = (__bf16)b.y; r[6] = (__bf16)b.z; r[7] = (__bf16)b.w;
  return r;
}

// ---------------------------------------------------------------------------
// Prep 1: fp32 -> bf16 convert of the 4 activation inputs (each 8192x512).
// ---------------------------------------------------------------------------
__global__ __launch_bounds__(256) void cvt_x(const float* __restrict__ q,
                                             const float* __restrict__ k,
                                             const float* __restrict__ v,
                                             const float* __restrict__ p,
                                             __bf16* __restrict__ dst) {
  const float* src = (blockIdx.y == 0) ? q
                   : (blockIdx.y == 1) ? k
                   : (blockIdx.y == 2) ? v : p;
  const size_t e = ((size_t)blockIdx.x * 256 + threadIdx.x) * 8;
  float4 a = *(const float4*)(src + e);
  float4 b = *(const float4*)(src + e + 4);
  *(bf16x8*)(dst + (size_t)blockIdx.y * 4194304 + e) = pack8(a, b);
}

// ---------------------------------------------------------------------------
// Prep 2: convert + transpose the 5 weight matrices to bf16 W^T[n][k].
// ---------------------------------------------------------------------------
__global__ __launch_bounds__(256) void cvt_w(const float* __restrict__ w0,
                                             const float* __restrict__ w1,
                                             const float* __restrict__ w2,
                                             const float* __restrict__ w3,
                                             const float* __restrict__ w4,
                                             __bf16* __restrict__ wt) {
  __shared__ float Ts[64][65];
  const float* W = (blockIdx.z == 0) ? w0
                 : (blockIdx.z == 1) ? w1
                 : (blockIdx.z == 2) ? w2
                 : (blockIdx.z == 3) ? w3 : w4;
  const int tid = threadIdx.x;
  const int kt = blockIdx.x * 64, nt = blockIdx.y * 64;
  const int r = tid >> 2, co = (tid & 3) * 16;
#pragma unroll
  for (int q = 0; q < 4; ++q)
    *(float4*)&Ts[r][co + q * 4] =
        *(const float4*)(W + (size_t)(kt + r) * 512 + nt + co + q * 4);
  __syncthreads();
  bf16x8 o0, o1;
#pragma unroll
  for (int q = 0; q < 8; ++q) o0[q] = (__bf16)Ts[co + q][r];
#pragma unroll
  for (int q = 0; q < 8; ++q) o1[q] = (__bf16)Ts[co + 8 + q][r];
  __bf16* dst = wt + (size_t)blockIdx.z * 262144 + (size_t)(nt + r) * 512 + kt + co;
  *(bf16x8*)dst = o0;
  *(bf16x8*)(dst + 8) = o1;
}

// ---------------------------------------------------------------------------
// bf16 GEMM: C[8192,512] = A[8192,512](bf16) @ Bt^T (Bt is [n][k] bf16).
// Tile 128x64, K-step 64, 256 thr. Epilogue modes:
//   0: dual scatter to [B,H,T,DK] bf16: o0 = acc+bias+u, o1 = acc+bias+v
//   1: single scatter bf16: o0 = acc+bias (bias may be null)
//   2: row-major fp32: o2 = acc+bias
// ---------------------------------------------------------------------------
__global__ __launch_bounds__(256) void gemm_bf16(
    const __bf16* __restrict__ A, const __bf16* __restrict__ Bt,
    const float* __restrict__ bias, const float* __restrict__ u,
    const float* __restrict__ v, __bf16* __restrict__ o0,
    __bf16* __restrict__ o1, float* __restrict__ o2, int mode) {
  __shared__ __bf16 As[128 * 72];
  __shared__ __bf16 Bs[64 * 72];
  const int tid = threadIdx.x;
  const int wave = tid >> 6, lane = tid & 63, l16 = lane & 15, quad = lane >> 4;
  const int m0 = blockIdx.y * 128, n0 = blockIdx.x * 64;

  const int ar = tid >> 1, ako = (tid & 1) * 32;
  const int br = tid >> 2, bko = (tid & 3) * 16;

  f32x4 acc[2][4];
#pragma unroll
  for (int rb = 0; rb < 2; ++rb)
#pragma unroll
    for (int cb = 0; cb < 4; ++cb) acc[rb][cb] = 0.f;

  for (int k0 = 0; k0 < 512; k0 += 64) {
    const __bf16* ap = A + (size_t)(m0 + ar) * 512 + k0 + ako;
    bf16x8 a0 = *(const bf16x8*)(ap);
    bf16x8 a1 = *(const bf16x8*)(ap + 8);
    bf16x8 a2 = *(const bf16x8*)(ap + 16);
    bf16x8 a3 = *(const bf16x8*)(ap + 24);
    const __bf16* bp = Bt + (size_t)(n0 + br) * 512 + k0 + bko;
    bf16x8 b0 = *(const bf16x8*)(bp);
    bf16x8 b1 = *(const bf16x8*)(bp + 8);
    __syncthreads();
    *(bf16x8*)&As[ar * 72 + ako] = a0;
    *(bf16x8*)&As[ar * 72 + ako + 8] = a1;
    *(bf16x8*)&As[ar * 72 + ako + 16] = a2;
    *(bf16x8*)&As[ar * 72 + ako + 24] = a3;
    *(bf16x8*)&Bs[br * 72 + bko] = b0;
    *(bf16x8*)&Bs[br * 72 + bko + 8] = b1;
    __syncthreads();
#pragma unroll
    for (int s = 0; s < 2; ++s) {
      bf16x8 af0 = *(const bf16x8*)&As[(wave * 32 + l16) * 72 + s * 32 + quad * 8];
      bf16x8 af1 = *(const bf16x8*)&As[(wave * 32 + 16 + l16) * 72 + s * 32 + quad * 8];
#pragma unroll
      for (int cb = 0; cb < 4; ++cb) {
        bf16x8 bf = *(const bf16x8*)&Bs[(cb * 16 + l16) * 72 + s * 32 + quad * 8];
        acc[0][cb] = MFMA16(af0, bf, acc[0][cb]);
        acc[1][cb] = MFMA16(af1, bf, acc[1][cb]);
      }
    }
  }

#pragma unroll
  for (int rb = 0; rb < 2; ++rb)
#pragma unroll
    for (int cb = 0; cb < 4; ++cb) {
      const int col = n0 + cb * 16 + l16;
      const float bv_ = bias ? bias[col] : 0.f;
#pragma unroll
      for (int r = 0; r < 4; ++r) {
        const int row = m0 + wave * 32 + rb * 16 + quad * 4 + r;
        const float val = acc[rb][cb][r] + bv_;
        if (mode == 2) {
          o2[(size_t)row * 512 + col] = val;
        } else {
          const int bb = row >> 10, tt = row & 1023;
          const int hh = col >> 6, dk = col & 63;
          const size_t idx = (((size_t)(bb * H_ + hh)) * T_ + tt) * DK_ + dk;
          if (mode == 0) {
            o0[idx] = (__bf16)(val + u[col]);
            o1[idx] = (__bf16)(val + v[col]);
          } else {
            o0[idx] = (__bf16)val;
          }
        }
      }
    }
}

// ---------------------------------------------------------------------------
// Fused MFMA attention, all-bf16 staging, pre-shifted R store:
//   R-GEMM value for (row, col) lands at Rs[row][col + row - 64]; gather is
//   then the conflict-free Rs[rr][dj], rr = di + (j-i>=2), zero at j-i==1.
// Per wave-strip only col-blocks 3-wave .. 7-wave are needed (5 of 8).
// ---------------------------------------------------------------------------
__global__ __launch_bounds__(256) void attn_mfma(
    const __bf16* __restrict__ qu, const __bf16* __restrict__ qv,
    const __bf16* __restrict__ kbuf, const __bf16* __restrict__ vbuf,
    const __bf16* __restrict__ pbuf, __bf16* __restrict__ ctx) {
  constexpr float SCALE = 0.044194173824159216f;  // 1/sqrt(512) (d_model)
  __shared__ __bf16 Kt[64 * 72];   // K[j][k]
  __shared__ __bf16 Vt[64 * 72];   // V^T[d][j]
  __shared__ __bf16 Pb[128 * 72];  // P band [o'][k]; aliased as Pa after use
  __shared__ __bf16 Rs[66 * 72];   // pre-shifted pos scores [rr][dj]

  const int tid = threadIdx.x;
  const int wave = tid >> 6, lane = tid & 63, l16 = lane & 15, quad = lane >> 4;
  const int i0 = blockIdx.x * 64, h = blockIdx.y, b = blockIdx.z;
  const size_t bh = ((size_t)(b * H_ + h)) * T_ * DK_;
  const __bf16* QU = qu + bh;
  const __bf16* QV = qv + bh;
  const __bf16* Kg = kbuf + bh;
  const __bf16* Vg = vbuf + bh;
  const __bf16* Pg = pbuf + bh;

  // A-fragments (already biased: qu = q+u, qv = q+v), kept all kernel.
  bf16x8 quA[2], qvw[2], qv4[2];
  {
    const int rw = i0 + wave * 16 + l16;
    const int r4g = i0 + 64 + l16;
    const int r4 = (r4g < T_) ? r4g : T_ - 1;
#pragma unroll
    for (int s = 0; s < 2; ++s) {
      const int ko = s * 32 + quad * 8;
      quA[s] = *(const bf16x8*)&QU[(size_t)rw * DK_ + ko];
      qvw[s] = *(const bf16x8*)&QV[(size_t)rw * DK_ + ko];
      qv4[s] = *(const bf16x8*)&QV[(size_t)r4 * DK_ + ko];
    }
  }

  f32x4 Oacc[4];
#pragma unroll
  for (int cb = 0; cb < 4; ++cb) Oacc[cb] = 0.f;
  float mrun[4], lrun[4];
#pragma unroll
  for (int r = 0; r < 4; ++r) { mrun[r] = -INFINITY; lrun[r] = 0.f; }

  const int rbase = wave * 16 + quad * 4;
  // staging index precompute
  const int kr = tid >> 2, kko = (tid & 3) * 16;       // K tile
  const int vd = tid & 63, vjb = (tid >> 6) * 16;      // V transpose
  const int po = tid >> 1, pko = (tid & 1) * 32;       // P band

  for (int jt = 0; jt < 16; ++jt) {
    const int j0 = jt * 64;
    int cstart = T_ - 65 + j0 - i0;
    if (cstart < 0) cstart += T_;
    if (cstart >= T_) cstart -= T_;

    __syncthreads();  // previous iteration's LDS reads complete
    {  // K tile [j][k]
      const __bf16* src = Kg + (size_t)(j0 + kr) * DK_ + kko;
      *(bf16x8*)&Kt[kr * 72 + kko] = *(const bf16x8*)src;
      *(bf16x8*)&Kt[kr * 72 + kko + 8] = *(const bf16x8*)(src + 8);
    }
    {  // V transposed [d][j]: 16 scalar ushort loads, 2 vector LDS writes
      bf16x8 w0, w1;
#pragma unroll
      for (int q = 0; q < 8; ++q) w0[q] = Vg[(size_t)(j0 + vjb + q) * DK_ + vd];
#pragma unroll
      for (int q = 0; q < 8; ++q) w1[q] = Vg[(size_t)(j0 + vjb + 8 + q) * DK_ + vd];
      *(bf16x8*)&Vt[vd * 72 + vjb] = w0;
      *(bf16x8*)&Vt[vd * 72 + vjb + 8] = w1;
    }
    {  // P band [o'][k]
      int prow = cstart + po;
      if (prow >= T_) prow -= T_;
      const __bf16* src = Pg + (size_t)prow * DK_ + pko;
      *(bf16x8*)&Pb[po * 72 + pko] = *(const bf16x8*)src;
      *(bf16x8*)&Pb[po * 72 + pko + 8] = *(const bf16x8*)(src + 8);
      *(bf16x8*)&Pb[po * 72 + pko + 16] = *(const bf16x8*)(src + 16);
      *(bf16x8*)&Pb[po * 72 + pko + 24] = *(const bf16x8*)(src + 24);
    }
    __syncthreads();

    // ---- content scores S = Qu K^T ----
    f32x4 sA[4];
#pragma unroll
    for (int cb = 0; cb < 4; ++cb) sA[cb] = 0.f;
#pragma unroll
    for (int s = 0; s < 2; ++s)
#pragma unroll
      for (int cb = 0; cb < 4; ++cb) {
        bf16x8 kf = *(const bf16x8*)&Kt[(cb * 16 + l16) * 72 + s * 32 + quad * 8];
        sA[cb] = MFMA16(quA[s], kf, sA[cb]);
      }

    // ---- R band GEMM, pre-shifted store (only needed col-blocks) ----
#pragma unroll
    for (int c = 0; c < 5; ++c) {
      const int cb = 3 - wave + c;
      f32x4 rc = 0.f;
#pragma unroll
      for (int s = 0; s < 2; ++s) {
        bf16x8 pf = *(const bf16x8*)&Pb[(cb * 16 + l16) * 72 + s * 32 + quad * 8];
        rc = MFMA16(qvw[s], pf, rc);
      }
      const int col = cb * 16 + l16;
#pragma unroll
      for (int rr = 0; rr < 4; ++rr) {
        const int dj = col + rbase + rr - 64;
        if (dj >= 0 && dj < 64) Rs[(rbase + rr) * 72 + dj] = (__bf16)rc[rr];
      }
    }
    {  // extra row 64 (q row i0+64), cols 0..63, one cb per wave
      const int cb = wave;
      f32x4 rc = 0.f;
#pragma unroll
      for (int s = 0; s < 2; ++s) {
        bf16x8 pf = *(const bf16x8*)&Pb[(cb * 16 + l16) * 72 + s * 32 + quad * 8];
        rc = MFMA16(qv4[s], pf, rc);
      }
      if (quad == 0) Rs[64 * 72 + cb * 16 + l16] = (__bf16)rc[0];
    }
    __syncthreads();

    // ---- add rel-shifted pos scores, scale ----
#pragma unroll
    for (int cb = 0; cb < 4; ++cb)
#pragma unroll
      for (int r = 0; r < 4; ++r) {
        const int di = rbase + r;
        const int dj = cb * 16 + l16;
        const int ji = (j0 + dj) - (i0 + di);
        float pos = 0.f;
        if (ji != 1) pos = (float)Rs[(di + (ji >= 2 ? 1 : 0)) * 72 + dj];
        sA[cb][r] = (sA[cb][r] + pos) * SCALE;
      }

    // ---- online softmax (row spread over 16 lanes of quad-group) ----
    __bf16* Pa = Pb;  // safe: Pb reads done before barrier above
#pragma unroll
    for (int r = 0; r < 4; ++r) {
      float tm = fmaxf(fmaxf(sA[0][r], sA[1][r]), fmaxf(sA[2][r], sA[3][r]));
      tm = fmaxf(tm, __shfl_xor(tm, 1));
      tm = fmaxf(tm, __shfl_xor(tm, 2));
      tm = fmaxf(tm, __shfl_xor(tm, 4));
      tm = fmaxf(tm, __shfl_xor(tm, 8));
      const float nm = fmaxf(mrun[r], tm);
      const float alpha = __expf(mrun[r] - nm);
      mrun[r] = nm;
      lrun[r] *= alpha;
#pragma unroll
      for (int cb = 0; cb < 4; ++cb) {
        Oacc[cb][r] *= alpha;
        const float w_ = __expf(sA[cb][r] - nm);
        lrun[r] += w_;
        Pa[(rbase + r) * 72 + cb * 16 + l16] = (__bf16)w_;
      }
    }

    // ---- O += Pa @ V (wave-local rows; in-wave LDS ordering suffices) ----
#pragma unroll
    for (int s = 0; s < 2; ++s) {
      bf16x8 ap = *(const bf16x8*)&Pa[(wave * 16 + l16) * 72 + s * 32 + quad * 8];
#pragma unroll
      for (int cb = 0; cb < 4; ++cb) {
        bf16x8 bv = *(const bf16x8*)&Vt[(cb * 16 + l16) * 72 + s * 32 + quad * 8];
        Oacc[cb] = MFMA16(ap, bv, Oacc[cb]);
      }
    }
  }

  // ---- epilogue ----
  float inv[4];
#pragma unroll
  for (int r = 0; r < 4; ++r) {
    float L = lrun[r];
    L += __shfl_xor(L, 1);
    L += __shfl_xor(L, 2);
    L += __shfl_xor(L, 4);
    L += __shfl_xor(L, 8);
    inv[r] = 1.f / L;
  }
#pragma unroll
  for (int cb = 0; cb < 4; ++cb)
#pragma unroll
    for (int r = 0; r < 4; ++r) {
      const int row = i0 + rbase + r;
      const int col = h * DK_ + cb * 16 + l16;
      ctx[((size_t)(b * T_ + row)) * D_ + col] = (__bf16)(Oacc[cb][r] * inv[r]);
    }
}

// ---------------------------------------------------------------------------
extern "C" void kernel_launch(void* const* d_in, const int* in_sizes, int n_in,
                              void* d_out, int out_size, void* d_ws,
                              size_t ws_size, hipStream_t stream) {
  const float* query = (const float*)d_in[0];
  const float* key   = (const float*)d_in[1];
  const float* value = (const float*)d_in[2];
  const float* pos   = (const float*)d_in[3];
  const float* Wq = (const float*)d_in[4];
  const float* bq = (const float*)d_in[5];
  const float* Wk = (const float*)d_in[6];
  const float* bk = (const float*)d_in[7];
  const float* Wv = (const float*)d_in[8];
  const float* bv = (const float*)d_in[9];
  const float* Wp = (const float*)d_in[10];
  const float* ub = (const float*)d_in[11];
  const float* vbias = (const float*)d_in[12];
  const float* Wo = (const float*)d_in[13];
  const float* bo = (const float*)d_in[14];
  float* out = (float*)d_out;

  // ws layout (bytes): Xb[4] (32MB) | qu,qv,kb,vb,pb (40MB) | Wt[5] (2.5MB)
  // ctx aliases Xb[0] (query's bf16 copy, consumed before attn runs).
  char* ws = (char*)d_ws;
  const size_t ACT = (size_t)8192 * 512 * 2;  // 8 MB
  __bf16* Xb = (__bf16*)ws;                   // 4 x ACT
  __bf16* quB = (__bf16*)(ws + 4 * ACT);
  __bf16* qvB = (__bf16*)(ws + 5 * ACT);
  __bf16* kB  = (__bf16*)(ws + 6 * ACT);
  __bf16* vB  = (__bf16*)(ws + 7 * ACT);
  __bf16* pB  = (__bf16*)(ws + 8 * ACT);
  __bf16* Wt  = (__bf16*)(ws + 9 * ACT);      // 5 x 512KB
  __bf16* ctx = Xb;                           // alias

  cvt_x<<<dim3(2048, 4), 256, 0, stream>>>(query, key, value, pos, Xb);
  cvt_w<<<dim3(8, 8, 5), 256, 0, stream>>>(Wq, Wk, Wv, Wp, Wo, Wt);

  const dim3 gg(8, 64);
  const size_t XN = (size_t)8192 * 512;  // elements per activation
  const size_t WN = (size_t)512 * 512;
  gemm_bf16<<<gg, 256, 0, stream>>>(Xb + 0 * XN, Wt + 0 * WN, bq, ub, vbias,
                                    quB, qvB, nullptr, 0);
  gemm_bf16<<<gg, 256, 0, stream>>>(Xb + 1 * XN, Wt + 1 * WN, bk, nullptr,
                                    nullptr, kB, nullptr, nullptr, 1);
  gemm_bf16<<<gg, 256, 0, stream>>>(Xb + 2 * XN, Wt + 2 * WN, bv, nullptr,
                                    nullptr, vB, nullptr, nullptr, 1);
  gemm_bf16<<<gg, 256, 0, stream>>>(Xb + 3 * XN, Wt + 3 * WN, nullptr, nullptr,
                                    nullptr, pB, nullptr, nullptr, 1);

  attn_mfma<<<dim3(T_ / 64, H_, B_), 256, 0, stream>>>(quB, qvB, kB, vB, pB,
                                                       ctx);

  gemm_bf16<<<gg, 256, 0, stream>>>(ctx, Wt + 4 * WN, bo, nullptr, nullptr,
                                    nullptr, nullptr, out, 2);
}

// Round 4
// 339.633 us; speedup vs baseline: 7.7063x; 1.0327x over previous
//
#include <hip/hip_runtime.h>

#define B_ 8
#define T_ 1024
#define D_ 512
#define H_ 8
#define DK_ 64

typedef __bf16 bf16x8 __attribute__((ext_vector_type(8)));
typedef float f32x4 __attribute__((ext_vector_type(4)));

#define MFMA16(a, b, c) __builtin_amdgcn_mfma_f32_16x16x32_bf16(a, b, c, 0, 0, 0)

__device__ __forceinline__ bf16x8 pack8(float4 a, float4 b) {
  bf16x8 r;
  r[0] = (__bf16)a.x; r[1] = (__bf16)a.y; r[2] = (__bf16)a.z; r[3] = (__bf16)a.w;
  r[4] = (__bf16)b.x; r[5] = (__bf16)b.y; r[6] = (__bf16)b.z; r[7] = (__bf16)b.w;
  return r;
}

// ---------------------------------------------------------------------------
// Prep 1: fp32 -> bf16 convert of the 4 activation inputs (each 8192x512).
// ---------------------------------------------------------------------------
__global__ __launch_bounds__(256) void cvt_x(const float* __restrict__ q,
                                             const float* __restrict__ k,
                                             const float* __restrict__ v,
                                             const float* __restrict__ p,
                                             __bf16* __restrict__ dst) {
  const float* src = (blockIdx.y == 0) ? q
                   : (blockIdx.y == 1) ? k
                   : (blockIdx.y == 2) ? v : p;
  const size_t e = ((size_t)blockIdx.x * 256 + threadIdx.x) * 8;
  float4 a = *(const float4*)(src + e);
  float4 b = *(const float4*)(src + e + 4);
  *(bf16x8*)(dst + (size_t)blockIdx.y * 4194304 + e) = pack8(a, b);
}

// ---------------------------------------------------------------------------
// Prep 2: convert + transpose the 5 weight matrices to bf16 W^T[n][k].
// ---------------------------------------------------------------------------
__global__ __launch_bounds__(256) void cvt_w(const float* __restrict__ w0,
                                             const float* __restrict__ w1,
                                             const float* __restrict__ w2,
                                             const float* __restrict__ w3,
                                             const float* __restrict__ w4,
                                             __bf16* __restrict__ wt) {
  __shared__ float Ts[64][65];
  const float* W = (blockIdx.z == 0) ? w0
                 : (blockIdx.z == 1) ? w1
                 : (blockIdx.z == 2) ? w2
                 : (blockIdx.z == 3) ? w3 : w4;
  const int tid = threadIdx.x;
  const int kt = blockIdx.x * 64, nt = blockIdx.y * 64;
  const int r = tid >> 2, co = (tid & 3) * 16;
#pragma unroll
  for (int q = 0; q < 4; ++q)
    *(float4*)&Ts[r][co + q * 4] =
        *(const float4*)(W + (size_t)(kt + r) * 512 + nt + co + q * 4);
  __syncthreads();
  bf16x8 o0, o1;
#pragma unroll
  for (int q = 0; q < 8; ++q) o0[q] = (__bf16)Ts[co + q][r];
#pragma unroll
  for (int q = 0; q < 8; ++q) o1[q] = (__bf16)Ts[co + 8 + q][r];
  __bf16* dst = wt + (size_t)blockIdx.z * 262144 + (size_t)(nt + r) * 512 + kt + co;
  *(bf16x8*)dst = o0;
  *(bf16x8*)(dst + 8) = o1;
}

// ---------------------------------------------------------------------------
// Prep 3: transpose v projection [B,H,T,DK] -> vT [B,H,DK,T].
// ---------------------------------------------------------------------------
__global__ __launch_bounds__(256) void transpose_v(const __bf16* __restrict__ vB,
                                                   __bf16* __restrict__ vT) {
  __shared__ __bf16 Ts[64 * 72];
  const int tid = threadIdx.x;
  const int t0 = blockIdx.x * 64;
  const size_t bh = (size_t)blockIdx.y * T_ * DK_;
  const int r = tid >> 2, co = (tid & 3) * 16;
  const __bf16* src = vB + bh + (size_t)(t0 + r) * DK_ + co;
  *(bf16x8*)&Ts[r * 72 + co] = *(const bf16x8*)src;
  *(bf16x8*)&Ts[r * 72 + co + 8] = *(const bf16x8*)(src + 8);
  __syncthreads();
  bf16x8 o0, o1;
#pragma unroll
  for (int e = 0; e < 8; ++e) o0[e] = Ts[(co + e) * 72 + r];
#pragma unroll
  for (int e = 0; e < 8; ++e) o1[e] = Ts[(co + 8 + e) * 72 + r];
  __bf16* dst = vT + bh + (size_t)r * T_ + t0 + co;
  *(bf16x8*)dst = o0;
  *(bf16x8*)(dst + 8) = o1;
}

// ---------------------------------------------------------------------------
// bf16 GEMM, register-prefetch pipelined. C[8192,512] = A @ Bt^T.
// phase 0 (grid.z = 0..3): A = Xb[z], W = Wt[z], scatter epilogues:
//   z0 -> quB/qvB (+bq +u / +v), z1 -> kB (+bk), z2 -> vB (+bv), z3 -> pB
// phase 1 (grid.z = 0): A = ctxA, W = Wt[4], out fp32 row-major (+bo)
// ---------------------------------------------------------------------------
__global__ __launch_bounds__(256) void gemm_bf16(
    const __bf16* __restrict__ Xb, const __bf16* __restrict__ ctxA,
    const __bf16* __restrict__ Wt, const float* __restrict__ bq,
    const float* __restrict__ bk, const float* __restrict__ bv,
    const float* __restrict__ bo, const float* __restrict__ u,
    const float* __restrict__ v, __bf16* __restrict__ quB,
    __bf16* __restrict__ qvB, __bf16* __restrict__ kB,
    __bf16* __restrict__ vB, __bf16* __restrict__ pB,
    float* __restrict__ out, int phase) {
  __shared__ __bf16 As[128 * 72];
  __shared__ __bf16 Bs[64 * 72];
  const int tid = threadIdx.x;
  const int z = blockIdx.z;
  const int wave = tid >> 6, lane = tid & 63, l16 = lane & 15, quad = lane >> 4;
  const int m0 = blockIdx.y * 128, n0 = blockIdx.x * 64;

  const __bf16* A = phase ? ctxA : Xb + (size_t)z * (8192 * 512);
  const __bf16* Bt = Wt + (size_t)(phase ? 4 : z) * (512 * 512);

  const int ar = tid >> 1, ako = (tid & 1) * 32;
  const int br = tid >> 2, bko = (tid & 3) * 16;
  const __bf16* aptr = A + (size_t)(m0 + ar) * 512 + ako;
  const __bf16* bptr = Bt + (size_t)(n0 + br) * 512 + bko;

  f32x4 acc[2][4];
#pragma unroll
  for (int rb = 0; rb < 2; ++rb)
#pragma unroll
    for (int cb = 0; cb < 4; ++cb) acc[rb][cb] = 0.f;

  // prefetch k0 = 0
  bf16x8 a0 = *(const bf16x8*)(aptr);
  bf16x8 a1 = *(const bf16x8*)(aptr + 8);
  bf16x8 a2 = *(const bf16x8*)(aptr + 16);
  bf16x8 a3 = *(const bf16x8*)(aptr + 24);
  bf16x8 b0 = *(const bf16x8*)(bptr);
  bf16x8 b1 = *(const bf16x8*)(bptr + 8);

  for (int k0 = 0; k0 < 512; k0 += 64) {
    __syncthreads();  // previous iteration's fragment reads done
    *(bf16x8*)&As[ar * 72 + ako] = a0;
    *(bf16x8*)&As[ar * 72 + ako + 8] = a1;
    *(bf16x8*)&As[ar * 72 + ako + 16] = a2;
    *(bf16x8*)&As[ar * 72 + ako + 24] = a3;
    *(bf16x8*)&Bs[br * 72 + bko] = b0;
    *(bf16x8*)&Bs[br * 72 + bko + 8] = b1;
    __syncthreads();
    if (k0 + 64 < 512) {  // prefetch next tile; waitcnt lands next iteration
      aptr += 64; bptr += 64;
      a0 = *(const bf16x8*)(aptr);
      a1 = *(const bf16x8*)(aptr + 8);
      a2 = *(const bf16x8*)(aptr + 16);
      a3 = *(const bf16x8*)(aptr + 24);
      b0 = *(const bf16x8*)(bptr);
      b1 = *(const bf16x8*)(bptr + 8);
    }
#pragma unroll
    for (int s = 0; s < 2; ++s) {
      bf16x8 af0 = *(const bf16x8*)&As[(wave * 32 + l16) * 72 + s * 32 + quad * 8];
      bf16x8 af1 = *(const bf16x8*)&As[(wave * 32 + 16 + l16) * 72 + s * 32 + quad * 8];
#pragma unroll
      for (int cb = 0; cb < 4; ++cb) {
        bf16x8 bf = *(const bf16x8*)&Bs[(cb * 16 + l16) * 72 + s * 32 + quad * 8];
        acc[0][cb] = MFMA16(af0, bf, acc[0][cb]);
        acc[1][cb] = MFMA16(af1, bf, acc[1][cb]);
      }
    }
  }

#pragma unroll
  for (int rb = 0; rb < 2; ++rb)
#pragma unroll
    for (int cb = 0; cb < 4; ++cb) {
      const int col = n0 + cb * 16 + l16;
#pragma unroll
      for (int r = 0; r < 4; ++r) {
        const int row = m0 + wave * 32 + rb * 16 + quad * 4 + r;
        const float val = acc[rb][cb][r];
        if (phase) {
          out[(size_t)row * 512 + col] = val + bo[col];
        } else {
          const int bb = row >> 10, tt = row & 1023;
          const int hh = col >> 6, dk = col & 63;
          const size_t idx = (((size_t)(bb * H_ + hh)) * T_ + tt) * DK_ + dk;
          if (z == 0) {
            const float t0 = val + bq[col];
            quB[idx] = (__bf16)(t0 + u[col]);
            qvB[idx] = (__bf16)(t0 + v[col]);
          } else if (z == 1) {
            kB[idx] = (__bf16)(val + bk[col]);
          } else if (z == 2) {
            vB[idx] = (__bf16)(val + bv[col]);
          } else {
            pB[idx] = (__bf16)val;
          }
        }
      }
    }
}

// ---------------------------------------------------------------------------
// Fused MFMA attention; register-prefetch pipelined staging; V from vT;
// Rs/Pa at stride 68 (scalar quad-strided ops and b128 frags conflict-free).
// ---------------------------------------------------------------------------
__global__ __launch_bounds__(256, 3) void attn_mfma(
    const __bf16* __restrict__ qu, const __bf16* __restrict__ qv,
    const __bf16* __restrict__ kbuf, const __bf16* __restrict__ vT,
    const __bf16* __restrict__ pbuf, __bf16* __restrict__ ctx) {
  constexpr float SCALE = 0.044194173824159216f;  // 1/sqrt(512) (d_model)
  __shared__ __bf16 Kt[64 * 72];   // K[j][k]
  __shared__ __bf16 Vt[64 * 72];   // V^T[d][j]
  __shared__ __bf16 Pb[128 * 72];  // P band [o'][k]; Pa aliases this region
  __shared__ __bf16 Rs[66 * 68];   // pre-shifted pos scores [rr][dj]

  const int tid = threadIdx.x;
  const int wave = tid >> 6, lane = tid & 63, l16 = lane & 15, quad = lane >> 4;
  const int i0 = blockIdx.x * 64, h = blockIdx.y, b = blockIdx.z;
  const size_t bh = ((size_t)(b * H_ + h)) * T_ * DK_;
  const __bf16* QU = qu + bh;
  const __bf16* QV = qv + bh;
  const __bf16* Kg = kbuf + bh;
  const __bf16* Vg = vT + bh;   // [DK][T]
  const __bf16* Pg = pbuf + bh;

  // A-fragments (pre-biased) held all kernel.
  bf16x8 quA[2], qvw[2], qv4[2];
  {
    const int rw = i0 + wave * 16 + l16;
    const int r4g = i0 + 64 + l16;
    const int r4 = (r4g < T_) ? r4g : T_ - 1;
#pragma unroll
    for (int s = 0; s < 2; ++s) {
      const int ko = s * 32 + quad * 8;
      quA[s] = *(const bf16x8*)&QU[(size_t)rw * DK_ + ko];
      qvw[s] = *(const bf16x8*)&QV[(size_t)rw * DK_ + ko];
      qv4[s] = *(const bf16x8*)&QV[(size_t)r4 * DK_ + ko];
    }
  }

  f32x4 Oacc[4];
#pragma unroll
  for (int cb = 0; cb < 4; ++cb) Oacc[cb] = 0.f;
  float mrun[4], lrun[4];
#pragma unroll
  for (int r = 0; r < 4; ++r) { mrun[r] = -INFINITY; lrun[r] = 0.f; }

  const int rbase = wave * 16 + quad * 4;
  const int kr = tid >> 2, kko = (tid & 3) * 16;   // K staging
  const int vd = tid >> 2, vjo = (tid & 3) * 16;   // V staging (from vT)
  const int po = tid >> 1, pko = (tid & 1) * 32;   // P staging

  bf16x8 kpre[2], vpre[2], ppre[4];
#define LOAD_KVP(JT)                                                          \
  {                                                                           \
    const int j0_ = (JT) * 64;                                                \
    const __bf16* ks_ = Kg + (size_t)(j0_ + kr) * DK_ + kko;                  \
    kpre[0] = *(const bf16x8*)ks_;                                            \
    kpre[1] = *(const bf16x8*)(ks_ + 8);                                      \
    const __bf16* vs_ = Vg + (size_t)vd * T_ + j0_ + vjo;                     \
    vpre[0] = *(const bf16x8*)vs_;                                            \
    vpre[1] = *(const bf16x8*)(vs_ + 8);                                      \
    int cs_ = T_ - 65 + j0_ - i0;                                             \
    if (cs_ < 0) cs_ += T_;                                                   \
    if (cs_ >= T_) cs_ -= T_;                                                 \
    int prow_ = cs_ + po;                                                     \
    if (prow_ >= T_) prow_ -= T_;                                             \
    const __bf16* ps_ = Pg + (size_t)prow_ * DK_ + pko;                       \
    ppre[0] = *(const bf16x8*)ps_;                                            \
    ppre[1] = *(const bf16x8*)(ps_ + 8);                                      \
    ppre[2] = *(const bf16x8*)(ps_ + 16);                                     \
    ppre[3] = *(const bf16x8*)(ps_ + 24);                                     \
  }

  LOAD_KVP(0)

  for (int jt = 0; jt < 16; ++jt) {
    const int j0 = jt * 64;
    __syncthreads();  // previous iteration's LDS reads complete
    *(bf16x8*)&Kt[kr * 72 + kko] = kpre[0];
    *(bf16x8*)&Kt[kr * 72 + kko + 8] = kpre[1];
    *(bf16x8*)&Vt[vd * 72 + vjo] = vpre[0];
    *(bf16x8*)&Vt[vd * 72 + vjo + 8] = vpre[1];
    *(bf16x8*)&Pb[po * 72 + pko] = ppre[0];
    *(bf16x8*)&Pb[po * 72 + pko + 8] = ppre[1];
    *(bf16x8*)&Pb[po * 72 + pko + 16] = ppre[2];
    *(bf16x8*)&Pb[po * 72 + pko + 24] = ppre[3];
    __syncthreads();
    if (jt < 15) LOAD_KVP(jt + 1)  // overlaps with compute below

    // ---- content scores S = Qu K^T ----
    f32x4 sA[4];
#pragma unroll
    for (int cb = 0; cb < 4; ++cb) sA[cb] = 0.f;
#pragma unroll
    for (int s = 0; s < 2; ++s)
#pragma unroll
      for (int cb = 0; cb < 4; ++cb) {
        bf16x8 kf = *(const bf16x8*)&Kt[(cb * 16 + l16) * 72 + s * 32 + quad * 8];
        sA[cb] = MFMA16(quA[s], kf, sA[cb]);
      }

    // ---- R band GEMM, pre-shifted store (only needed col-blocks) ----
#pragma unroll
    for (int c = 0; c < 5; ++c) {
      const int cb = 3 - wave + c;
      f32x4 rc = 0.f;
#pragma unroll
      for (int s = 0; s < 2; ++s) {
        bf16x8 pf = *(const bf16x8*)&Pb[(cb * 16 + l16) * 72 + s * 32 + quad * 8];
        rc = MFMA16(qvw[s], pf, rc);
      }
      const int col = cb * 16 + l16;
#pragma unroll
      for (int rr = 0; rr < 4; ++rr) {
        const int dj = col + rbase + rr - 64;
        if (dj >= 0 && dj < 64) Rs[(rbase + rr) * 68 + dj] = (__bf16)rc[rr];
      }
    }
    {  // extra row 64 (q row i0+64), cols 0..63, one cb per wave
      const int cb = wave;
      f32x4 rc = 0.f;
#pragma unroll
      for (int s = 0; s < 2; ++s) {
        bf16x8 pf = *(const bf16x8*)&Pb[(cb * 16 + l16) * 72 + s * 32 + quad * 8];
        rc = MFMA16(qv4[s], pf, rc);
      }
      if (quad == 0) Rs[64 * 68 + cb * 16 + l16] = (__bf16)rc[0];
    }
    __syncthreads();

    // ---- add rel-shifted pos scores, scale ----
#pragma unroll
    for (int cb = 0; cb < 4; ++cb)
#pragma unroll
      for (int r = 0; r < 4; ++r) {
        const int di = rbase + r;
        const int dj = cb * 16 + l16;
        const int ji = (j0 + dj) - (i0 + di);
        float pos = 0.f;
        if (ji != 1) pos = (float)Rs[(di + (ji >= 2 ? 1 : 0)) * 68 + dj];
        sA[cb][r] = (sA[cb][r] + pos) * SCALE;
      }

    // ---- online softmax ----
    __bf16* Pa = Pb;  // alias; stride 68. Pb LDS reads done pre-barrier.
#pragma unroll
    for (int r = 0; r < 4; ++r) {
      float tm = fmaxf(fmaxf(sA[0][r], sA[1][r]), fmaxf(sA[2][r], sA[3][r]));
      tm = fmaxf(tm, __shfl_xor(tm, 1));
      tm = fmaxf(tm, __shfl_xor(tm, 2));
      tm = fmaxf(tm, __shfl_xor(tm, 4));
      tm = fmaxf(tm, __shfl_xor(tm, 8));
      const float nm = fmaxf(mrun[r], tm);
      const float alpha = __expf(mrun[r] - nm);
      mrun[r] = nm;
      lrun[r] *= alpha;
#pragma unroll
      for (int cb = 0; cb < 4; ++cb) {
        Oacc[cb][r] *= alpha;
        const float w_ = __expf(sA[cb][r] - nm);
        lrun[r] += w_;
        Pa[(rbase + r) * 68 + cb * 16 + l16] = (__bf16)w_;
      }
    }

    // ---- O += Pa @ V (wave-local rows; in-wave LDS ordering suffices) ----
#pragma unroll
    for (int s = 0; s < 2; ++s) {
      bf16x8 ap = *(const bf16x8*)&Pa[(wave * 16 + l16) * 68 + s * 32 + quad * 8];
#pragma unroll
      for (int cb = 0; cb < 4; ++cb) {
        bf16x8 bv = *(const bf16x8*)&Vt[(cb * 16 + l16) * 72 + s * 32 + quad * 8];
        Oacc[cb] = MFMA16(ap, bv, Oacc[cb]);
      }
    }
  }

  // ---- epilogue ----
  float inv[4];
#pragma unroll
  for (int r = 0; r < 4; ++r) {
    float L = lrun[r];
    L += __shfl_xor(L, 1);
    L += __shfl_xor(L, 2);
    L += __shfl_xor(L, 4);
    L += __shfl_xor(L, 8);
    inv[r] = 1.f / L;
  }
#pragma unroll
  for (int cb = 0; cb < 4; ++cb)
#pragma unroll
    for (int r = 0; r < 4; ++r) {
      const int row = i0 + rbase + r;
      const int col = h * DK_ + cb * 16 + l16;
      ctx[((size_t)(b * T_ + row)) * D_ + col] = (__bf16)(Oacc[cb][r] * inv[r]);
    }
}

// ---------------------------------------------------------------------------
extern "C" void kernel_launch(void* const* d_in, const int* in_sizes, int n_in,
                              void* d_out, int out_size, void* d_ws,
                              size_t ws_size, hipStream_t stream) {
  const float* query = (const float*)d_in[0];
  const float* key   = (const float*)d_in[1];
  const float* value = (const float*)d_in[2];
  const float* pos   = (const float*)d_in[3];
  const float* Wq = (const float*)d_in[4];
  const float* bq = (const float*)d_in[5];
  const float* Wk = (const float*)d_in[6];
  const float* bk = (const float*)d_in[7];
  const float* Wv = (const float*)d_in[8];
  const float* bv = (const float*)d_in[9];
  const float* Wp = (const float*)d_in[10];
  const float* ub = (const float*)d_in[11];
  const float* vbias = (const float*)d_in[12];
  const float* Wo = (const float*)d_in[13];
  const float* bo = (const float*)d_in[14];
  float* out = (float*)d_out;

  // ws layout (bytes): Xb[4] (32MB) | qu,qv,kb,vb,pb (40MB) | Wt[5] (2.5MB)
  // vT aliases Xb[1] (key bf16, consumed by projection before transpose).
  // ctx aliases Xb[0] (query bf16, consumed by projection before attn).
  char* ws = (char*)d_ws;
  const size_t ACT = (size_t)8192 * 512 * 2;  // 8 MB
  const size_t XN = (size_t)8192 * 512;
  __bf16* Xb = (__bf16*)ws;                   // 4 x ACT
  __bf16* quB = (__bf16*)(ws + 4 * ACT);
  __bf16* qvB = (__bf16*)(ws + 5 * ACT);
  __bf16* kB  = (__bf16*)(ws + 6 * ACT);
  __bf16* vB  = (__bf16*)(ws + 7 * ACT);
  __bf16* pB  = (__bf16*)(ws + 8 * ACT);
  __bf16* Wt  = (__bf16*)(ws + 9 * ACT);      // 5 x 512KB
  __bf16* vT  = Xb + 1 * XN;                  // alias (key slot)
  __bf16* ctx = Xb;                           // alias (query slot)

  cvt_x<<<dim3(2048, 4), 256, 0, stream>>>(query, key, value, pos, Xb);
  cvt_w<<<dim3(8, 8, 5), 256, 0, stream>>>(Wq, Wk, Wv, Wp, Wo, Wt);

  // fused 4-way projection GEMM
  gemm_bf16<<<dim3(8, 64, 4), 256, 0, stream>>>(
      Xb, nullptr, Wt, bq, bk, bv, bo, ub, vbias, quB, qvB, kB, vB, pB,
      nullptr, 0);

  transpose_v<<<dim3(16, 64), 256, 0, stream>>>(vB, vT);

  attn_mfma<<<dim3(T_ / 64, H_, B_), 256, 0, stream>>>(quB, qvB, kB, vT, pB,
                                                       ctx);

  gemm_bf16<<<dim3(8, 64, 1), 256, 0, stream>>>(
      nullptr, ctx, Wt, bq, bk, bv, bo, ub, vbias, quB, qvB, kB, vB, pB,
      out, 1);
}